// Round 1
// baseline (466.700 us; speedup 1.0000x reference)
//
#include <hip/hip_runtime.h>
#include <hip/hip_bf16.h>

#define NIMG 8
#define NC   80
#define NL   256
#define HWQ  15200
#define TOPK 1000
#define CAP  2048
#define NPOST 100
#define TOTAL (NIMG * HWQ * NC)   // 9,728,000

__device__ __forceinline__ unsigned flipKey(float f) {
    unsigned u = __float_as_uint(f);
    return u ^ (((unsigned)((int)u >> 31)) | 0x80000000u);
}
__device__ __forceinline__ float unflipKey(unsigned k) {
    unsigned u = k ^ ((k & 0x80000000u) ? 0x80000000u : 0xFFFFFFFFu);
    return __uint_as_float(u);
}
__device__ __forceinline__ float sigmoidf(float x) {
    return 1.0f / (1.0f + expf(-x));
}

// ---- prep: extract nonzero (token, weight) lists per class, ascending l ----
__global__ void kprep(const float* __restrict__ pm, unsigned* nnz,
                      unsigned* tok, float* wt) {
    int c = blockIdx.x * blockDim.x + threadIdx.x;
    if (c >= NC) return;
    int cnt = 0;
    for (int l = 0; l < NL; ++l) {
        float v = pm[c * NL + l];
        if (v != 0.0f) { tok[cnt * NC + c] = l; wt[cnt * NC + c] = v; cnt++; }
    }
    nnz[c] = cnt;
}

// ---- centerness sigmoid ----
__global__ void kctr(const float* __restrict__ cent, float* ctr) {
    int i = blockIdx.x * blockDim.x + threadIdx.x;
    if (i < NIMG * HWQ) ctr[i] = sigmoidf(cent[i]);
}

// ---- fused masked score per (n,k,c) ----
__global__ void kscore(const float* __restrict__ dp, const float* __restrict__ ctr,
                       const unsigned* __restrict__ nnz, const unsigned* __restrict__ tok,
                       const float* __restrict__ wt, float* __restrict__ scores) {
    int e = blockIdx.x * blockDim.x + threadIdx.x;
    if (e >= TOTAL) return;
    int c  = e % NC;
    int nk = e / NC;
    const float* row = dp + (long long)nk * NL;
    int m = nnz[c];
    float acc = 0.0f;
    for (int t = 0; t < m; ++t) {
        float x = row[tok[t * NC + c]];
        acc += sigmoidf(x) * wt[t * NC + c];
    }
    float fused  = acc * ctr[nk];
    scores[e] = (acc > 0.05f) ? fused : -1.0f;
}

// ---- coarse histogram: top 12 bits of sortable key ----
__global__ void khist1(const float* __restrict__ scores, unsigned* gh) {
    __shared__ unsigned h[4096];
    for (int i = threadIdx.x; i < 4096; i += blockDim.x) h[i] = 0;
    __syncthreads();
    int n = blockIdx.y;
    int per = (HWQ * NC + gridDim.x - 1) / gridDim.x;
    int base = blockIdx.x * per;
    int end = min(base + per, HWQ * NC);
    const float* s = scores + (long long)n * HWQ * NC;
    for (int i = base + threadIdx.x; i < end; i += blockDim.x) {
        unsigned key = flipKey(s[i]);
        atomicAdd(&h[key >> 20], 1u);
    }
    __syncthreads();
    for (int i = threadIdx.x; i < 4096; i += blockDim.x)
        if (h[i]) atomicAdd(&gh[n * 4096 + i], h[i]);
}

// ---- find coarse bucket containing rank TOPK ----
__global__ void kfind1(const unsigned* __restrict__ gh, unsigned* meta) {
    __shared__ unsigned h[4096];
    __shared__ unsigned psum[256];
    int n = blockIdx.x;
    for (int i = threadIdx.x; i < 4096; i += 256) h[i] = gh[n * 4096 + i];
    __syncthreads();
    unsigned s = 0;
    for (int i = 0; i < 16; ++i) s += h[threadIdx.x * 16 + i];
    psum[threadIdx.x] = s;
    __syncthreads();
    if (threadIdx.x == 0) {
        unsigned cum = 0, above = 0; int B = 0; bool done = false;
        for (int seg = 255; seg >= 0 && !done; --seg) {
            if (cum + psum[seg] >= TOPK) {
                for (int b = seg * 16 + 15; b >= seg * 16; --b) {
                    if (cum + h[b] >= TOPK) { B = b; above = cum; done = true; break; }
                    cum += h[b];
                }
            } else cum += psum[seg];
        }
        meta[n] = (unsigned)B;
        meta[8 + n] = above;
    }
}

// ---- fine histogram: next 12 bits, only for boundary coarse bucket ----
__global__ void khist2(const float* __restrict__ scores,
                       const unsigned* __restrict__ meta, unsigned* fh) {
    int i = blockIdx.x * blockDim.x + threadIdx.x;
    if (i >= TOTAL) return;
    int n = i / (HWQ * NC);
    unsigned key = flipKey(scores[i]);
    if ((key >> 20) == meta[n])
        atomicAdd(&fh[n * 4096 + ((key >> 8) & 0xFFFu)], 1u);
}

// ---- find fine bucket -> final 24-bit threshold ----
__global__ void kfind2(const unsigned* __restrict__ fh, unsigned* meta) {
    __shared__ unsigned h[4096];
    __shared__ unsigned psum[256];
    int n = blockIdx.x;
    for (int i = threadIdx.x; i < 4096; i += 256) h[i] = fh[n * 4096 + i];
    __syncthreads();
    unsigned s = 0;
    for (int i = 0; i < 16; ++i) s += h[threadIdx.x * 16 + i];
    psum[threadIdx.x] = s;
    __syncthreads();
    if (threadIdx.x == 0) {
        unsigned cum = meta[8 + n]; int B2 = 0; bool done = false;
        for (int seg = 255; seg >= 0 && !done; --seg) {
            if (cum + psum[seg] >= TOPK) {
                for (int b = seg * 16 + 15; b >= seg * 16; --b) {
                    if (cum + h[b] >= TOPK) { B2 = b; done = true; break; }
                    cum += h[b];
                }
            } else cum += psum[seg];
        }
        meta[16 + n] = ((meta[n] << 12) | (unsigned)B2) << 8;
    }
}

// ---- compact candidates >= threshold into per-image buffers ----
__global__ void kcompact(const float* __restrict__ scores,
                         const unsigned* __restrict__ meta,
                         unsigned* cnt, unsigned long long* cand) {
    int i = blockIdx.x * blockDim.x + threadIdx.x;
    if (i >= TOTAL) return;
    int n  = i / (HWQ * NC);
    int li = i % (HWQ * NC);
    unsigned key = flipKey(scores[i]);
    if (key >= meta[16 + n]) {
        unsigned p = atomicAdd(&cnt[n], 1u);
        if (p < CAP)
            cand[n * CAP + p] = ((unsigned long long)key << 32) | (unsigned)(~li);
    }
}

// ---- per-image: exact sort, decode, class-decomposed greedy NMS, output ----
__global__ void __launch_bounds__(256)
knms(const unsigned long long* __restrict__ cand, const unsigned* __restrict__ cnt,
     const float* __restrict__ anchors, const float* __restrict__ breg,
     float* __restrict__ outBoxes, float* __restrict__ outScores,
     float* __restrict__ outLabels) {
    __shared__ unsigned long long sbuf[CAP];
    __shared__ float bx[TOPK][4];
    __shared__ float obx[TOPK][4];
    __shared__ float area[TOPK];
    __shared__ unsigned short lbl[TOPK];
    __shared__ unsigned char  keepf[TOPK];
    __shared__ unsigned short clist[TOPK];
    __shared__ unsigned short cstart[NC + 1];
    __shared__ unsigned short ccnt[NC];
    __shared__ unsigned short outIdx[NPOST];
    __shared__ int nkept;

    int n = blockIdx.x;
    int M = min(cnt[n], (unsigned)CAP);
    for (int i = threadIdx.x; i < CAP; i += 256)
        sbuf[i] = (i < M) ? cand[n * CAP + i] : 0ULL;
    __syncthreads();

    // bitonic sort, descending (value desc, then idx asc via ~idx in low bits)
    for (int k = 2; k <= CAP; k <<= 1) {
        for (int j = k >> 1; j > 0; j >>= 1) {
            for (int i = threadIdx.x; i < CAP; i += 256) {
                int l = i ^ j;
                if (l > i) {
                    unsigned long long a = sbuf[i], b = sbuf[l];
                    bool sw = ((i & k) == 0) ? (a < b) : (a > b);
                    if (sw) { sbuf[i] = b; sbuf[l] = a; }
                }
            }
            __syncthreads();
        }
    }

    // decode top-1000
    for (int r = threadIdx.x; r < TOPK; r += 256) {
        unsigned long long e = sbuf[r];
        unsigned key = (unsigned)(e >> 32);
        bool real = (r < M) && (key > 0x80000000u);   // masked value > 0 <=> cand
        unsigned li = ~(unsigned)(e & 0xFFFFFFFFu);
        int k = (int)(li / NC), c = (int)(li % NC);
        int label = c + 1;
        float x1 = 0, y1 = 0, x2 = 0, y2 = 0;
        bool val = false;
        if (real) {
            float a0 = anchors[k * 4 + 0], a1 = anchors[k * 4 + 1];
            float a2 = anchors[k * 4 + 2], a3 = anchors[k * 4 + 3];
            float r0 = breg[(n * 4 + 0) * HWQ + k];
            float r1 = breg[(n * 4 + 1) * HWQ + k];
            float r2 = breg[(n * 4 + 2) * HWQ + k];
            float r3 = breg[(n * 4 + 3) * HWQ + k];
            float aw = a2 - a0, ah = a3 - a1;
            float acx = a0 + 0.5f * aw, acy = a1 + 0.5f * ah;
            float dx = r0 / 10.0f, dy = r1 / 10.0f;
            float dw = fminf(r2 / 5.0f, 4.135166556742356f);
            float dh = fminf(r3 / 5.0f, 4.135166556742356f);
            float pcx = dx * aw + acx, pcy = dy * ah + acy;
            float pw = expf(dw) * aw, ph = expf(dh) * ah;
            x1 = fminf(fmaxf(pcx - 0.5f * pw, 0.0f), 1216.0f);
            y1 = fminf(fmaxf(pcy - 0.5f * ph, 0.0f), 800.0f);
            x2 = fminf(fmaxf(pcx + 0.5f * pw, 0.0f), 1216.0f);
            y2 = fminf(fmaxf(pcy + 0.5f * ph, 0.0f), 800.0f);
            val = (x2 - x1 > 0.0f) && (y2 - y1 > 0.0f);
        }
        bx[r][0] = x1; bx[r][1] = y1; bx[r][2] = x2; bx[r][3] = y2;
        float off = (float)label * 10000.0f;   // replicate offset-then-round
        float o0 = x1 + off, o1 = y1 + off, o2 = x2 + off, o3 = y2 + off;
        obx[r][0] = o0; obx[r][1] = o1; obx[r][2] = o2; obx[r][3] = o3;
        area[r] = (o2 - o0) * (o3 - o1);
        lbl[r] = real ? (unsigned short)label : (unsigned short)0;
        keepf[r] = val ? 1 : 0;
    }
    __syncthreads();

    // per-class candidate lists (order preserved)
    if (threadIdx.x < NC) {
        int cc = 0;
        for (int r = 0; r < TOPK; ++r)
            if (lbl[r] == threadIdx.x + 1) cc++;
        ccnt[threadIdx.x] = (unsigned short)cc;
    }
    __syncthreads();
    if (threadIdx.x == 0) {
        unsigned s = 0;
        for (int c = 0; c < NC; ++c) { cstart[c] = (unsigned short)s; s += ccnt[c]; }
        cstart[NC] = (unsigned short)s;
    }
    __syncthreads();
    if (threadIdx.x < NC) {
        int w = cstart[threadIdx.x];
        for (int r = 0; r < TOPK; ++r)
            if (lbl[r] == threadIdx.x + 1) clist[w++] = (unsigned short)r;
    }
    __syncthreads();

    // greedy NMS, one thread per class (cross-class IoU is exactly 0)
    if (threadIdx.x < NC) {
        int s0 = cstart[threadIdx.x];
        int s1 = s0 + ccnt[threadIdx.x];
        for (int a = s0; a < s1; ++a) {
            int ia = clist[a];
            if (!keepf[ia]) continue;
            float A0 = obx[ia][0], A1 = obx[ia][1], A2 = obx[ia][2], A3 = obx[ia][3];
            float Aa = area[ia];
            for (int b = a + 1; b < s1; ++b) {
                int ib = clist[b];
                if (!keepf[ib]) continue;
                float iw = fminf(A2, obx[ib][2]) - fmaxf(A0, obx[ib][0]);
                float ih = fminf(A3, obx[ib][3]) - fmaxf(A1, obx[ib][1]);
                float inter = fmaxf(iw, 0.0f) * fmaxf(ih, 0.0f);
                float denom = Aa + area[ib] - inter + 1e-6f;
                if (inter / denom > 0.6f) keepf[ib] = 0;
            }
        }
    }
    __syncthreads();

    // first 100 kept in sorted order
    if (threadIdx.x == 0) {
        int p = 0;
        for (int r = 0; r < TOPK && p < NPOST; ++r)
            if (keepf[r]) outIdx[p++] = (unsigned short)r;
        nkept = p;
    }
    __syncthreads();

    for (int q = threadIdx.x; q < NPOST; q += 256) {
        float b0 = 0, b1 = 0, b2 = 0, b3 = 0, sc = 0, lab = 0;
        if (q < nkept) {
            int r = outIdx[q];
            b0 = bx[r][0]; b1 = bx[r][1]; b2 = bx[r][2]; b3 = bx[r][3];
            float fused = unflipKey((unsigned)(sbuf[r] >> 32));
            sc = sqrtf(fmaxf(fused, 0.0f));
            lab = (float)lbl[r];
        }
        outBoxes[(n * NPOST + q) * 4 + 0] = b0;
        outBoxes[(n * NPOST + q) * 4 + 1] = b1;
        outBoxes[(n * NPOST + q) * 4 + 2] = b2;
        outBoxes[(n * NPOST + q) * 4 + 3] = b3;
        outScores[n * NPOST + q] = sc;
        outLabels[n * NPOST + q] = lab;
    }
}

extern "C" void kernel_launch(void* const* d_in, const int* in_sizes, int n_in,
                              void* d_out, int out_size, void* d_ws, size_t ws_size,
                              hipStream_t stream) {
    const float* breg = (const float*)d_in[0];   // [8,4,100,152]
    const float* cent = (const float*)d_in[1];   // [8,1,100,152]
    // d_in[2] box_cls: unused by reference
    const float* dp   = (const float*)d_in[3];   // [8,15200,256]
    const float* anc  = (const float*)d_in[4];   // [15200,4]
    const float* pm   = (const float*)d_in[5];   // [80,256]

    char* ws = (char*)d_ws;
    size_t off_scores = 0;                               // 38,912,000 B
    size_t off_ctr    = off_scores + (size_t)TOTAL * 4;  // 486,400 B
    size_t off_gh     = off_ctr + (size_t)NIMG * HWQ * 4;        // 131,072
    size_t off_fh     = off_gh + (size_t)NIMG * 4096 * 4;        // 131,072
    size_t off_cnt    = off_fh + (size_t)NIMG * 4096 * 4;        // 32
    size_t off_meta   = off_cnt + 256;                           // 96 (padded)
    size_t off_cand   = off_meta + 256;                          // 131,072
    size_t off_nnz    = off_cand + (size_t)NIMG * CAP * 8;       // 320
    size_t off_tok    = off_nnz + 512;                           // 81,920
    size_t off_wt     = off_tok + (size_t)NC * NL * 4;           // 81,920
    size_t needed     = off_wt + (size_t)NC * NL * 4;
    if (ws_size < needed) return;

    float*    scores = (float*)(ws + off_scores);
    float*    ctr    = (float*)(ws + off_ctr);
    unsigned* gh     = (unsigned*)(ws + off_gh);
    unsigned* fh     = (unsigned*)(ws + off_fh);
    unsigned* cnt    = (unsigned*)(ws + off_cnt);
    unsigned* meta   = (unsigned*)(ws + off_meta);
    unsigned long long* cand = (unsigned long long*)(ws + off_cand);
    unsigned* nnz    = (unsigned*)(ws + off_nnz);
    unsigned* tok    = (unsigned*)(ws + off_tok);
    float*    wt     = (float*)(ws + off_wt);

    // zero histograms + counters (gh, fh, cnt are contiguous)
    hipMemsetAsync(ws + off_gh, 0,
                   (size_t)NIMG * 4096 * 4 * 2 + 32, stream);

    kprep<<<1, 128, 0, stream>>>(pm, nnz, tok, wt);
    kctr<<<(NIMG * HWQ + 255) / 256, 256, 0, stream>>>(cent, ctr);
    kscore<<<(TOTAL + 255) / 256, 256, 0, stream>>>(dp, ctr, nnz, tok, wt, scores);
    khist1<<<dim3(64, NIMG), 256, 0, stream>>>(scores, gh);
    kfind1<<<NIMG, 256, 0, stream>>>(gh, meta);
    khist2<<<(TOTAL + 255) / 256, 256, 0, stream>>>(scores, meta, fh);
    kfind2<<<NIMG, 256, 0, stream>>>(fh, meta);
    kcompact<<<(TOTAL + 255) / 256, 256, 0, stream>>>(scores, meta, cnt, cand);

    float* outBoxes  = (float*)d_out;                       // 8*100*4
    float* outScores = outBoxes + NIMG * NPOST * 4;         // 8*100
    float* outLabels = outScores + NIMG * NPOST;            // 8*100
    knms<<<NIMG, 256, 0, stream>>>(cand, cnt, anc, breg,
                                   outBoxes, outScores, outLabels);
}

// Round 2
// 371.702 us; speedup vs baseline: 1.2556x; 1.2556x over previous
//
#include <hip/hip_runtime.h>
#include <hip/hip_bf16.h>

#define NIMG 8
#define NC   80
#define NL   256
#define HWQ  15200
#define TOPK 1000
#define CAP  2048
#define NPOST 100
#define PERIMG (HWQ * NC)          // 1,216,000
#define TOTAL (NIMG * PERIMG)      // 9,728,000
#define SBLK 95                    // score blocks per image; 1216000/95 = 12800 = 50*256

__device__ __forceinline__ unsigned flipKey(float f) {
    unsigned u = __float_as_uint(f);
    return u ^ (((unsigned)((int)u >> 31)) | 0x80000000u);
}
__device__ __forceinline__ float unflipKey(unsigned k) {
    unsigned u = k ^ ((k & 0x80000000u) ? 0x80000000u : 0xFFFFFFFFu);
    return __uint_as_float(u);
}
__device__ __forceinline__ float sigmoidf(float x) {
    return 1.0f / (1.0f + expf(-x));
}

// ---- prep: extract nonzero (token, weight) lists per class, ascending l ----
__global__ void kprep(const float* __restrict__ pm, unsigned* nnz,
                      unsigned* tok, float* wt) {
    int c = blockIdx.x * blockDim.x + threadIdx.x;
    if (c >= NC) return;
    int cnt = 0;
    for (int l = 0; l < NL; ++l) {
        float v = pm[c * NL + l];
        if (v != 0.0f) { tok[cnt * NC + c] = l; wt[cnt * NC + c] = v; cnt++; }
    }
    nnz[c] = cnt;
}

// ---- centerness sigmoid ----
__global__ void kctr(const float* __restrict__ cent, float* ctr) {
    int i = blockIdx.x * blockDim.x + threadIdx.x;
    if (i < NIMG * HWQ) ctr[i] = sigmoidf(cent[i]);
}

// ---- fused: masked score per (n,k,c) + coarse 12-bit histogram ----
__global__ void __launch_bounds__(256)
kscoreh(const float* __restrict__ dp, const float* __restrict__ ctr,
        const unsigned* __restrict__ nnz, const unsigned* __restrict__ tok,
        const float* __restrict__ wt, float* __restrict__ scores,
        unsigned* __restrict__ gh) {
    __shared__ unsigned h[4096];
    for (int i = threadIdx.x; i < 4096; i += 256) h[i] = 0;
    __syncthreads();
    int n  = blockIdx.x / SBLK;
    int lb = blockIdx.x % SBLK;
    const int PER = PERIMG / SBLK;           // 12800
    int base = n * PERIMG + lb * PER;
    for (int it = 0; it < PER / 256; ++it) { // 50, all lanes always active
        int e = base + it * 256 + threadIdx.x;
        int c  = e % NC;
        int nk = e / NC;
        const float* row = dp + (long long)nk * NL;
        int m = nnz[c];
        float acc = 0.0f;
        for (int t = 0; t < m; ++t)
            acc += sigmoidf(row[tok[t * NC + c]]) * wt[t * NC + c];
        float fused = acc * ctr[nk];
        float sc = (acc > 0.05f) ? fused : -1.0f;
        scores[e] = sc;
        atomicAdd(&h[flipKey(sc) >> 20], 1u);
    }
    __syncthreads();
    for (int i = threadIdx.x; i < 4096; i += 256)
        if (h[i]) atomicAdd(&gh[n * 4096 + i], h[i]);
}

// ---- find coarse bucket containing rank TOPK ----
__global__ void kfind1(const unsigned* __restrict__ gh, unsigned* meta) {
    __shared__ unsigned h[4096];
    __shared__ unsigned psum[256];
    int n = blockIdx.x;
    for (int i = threadIdx.x; i < 4096; i += 256) h[i] = gh[n * 4096 + i];
    __syncthreads();
    unsigned s = 0;
    for (int i = 0; i < 16; ++i) s += h[threadIdx.x * 16 + i];
    psum[threadIdx.x] = s;
    __syncthreads();
    if (threadIdx.x == 0) {
        unsigned cum = 0, above = 0; int B = 0; bool done = false;
        for (int seg = 255; seg >= 0 && !done; --seg) {
            if (cum + psum[seg] >= TOPK) {
                for (int b = seg * 16 + 15; b >= seg * 16; --b) {
                    if (cum + h[b] >= TOPK) { B = b; above = cum; done = true; break; }
                    cum += h[b];
                }
            } else cum += psum[seg];
        }
        meta[n] = (unsigned)B;
        meta[8 + n] = above;
    }
}

// ---- fine histogram: next 12 bits, only for boundary coarse bucket ----
__global__ void khist2(const float* __restrict__ scores,
                       const unsigned* __restrict__ meta, unsigned* fh) {
    int i = blockIdx.x * blockDim.x + threadIdx.x;
    if (i >= TOTAL) return;
    int n = i / PERIMG;
    unsigned key = flipKey(scores[i]);
    if ((key >> 20) == meta[n])
        atomicAdd(&fh[n * 4096 + ((key >> 8) & 0xFFFu)], 1u);
}

// ---- find fine bucket -> final 24-bit threshold ----
__global__ void kfind2(const unsigned* __restrict__ fh, unsigned* meta) {
    __shared__ unsigned h[4096];
    __shared__ unsigned psum[256];
    int n = blockIdx.x;
    for (int i = threadIdx.x; i < 4096; i += 256) h[i] = fh[n * 4096 + i];
    __syncthreads();
    unsigned s = 0;
    for (int i = 0; i < 16; ++i) s += h[threadIdx.x * 16 + i];
    psum[threadIdx.x] = s;
    __syncthreads();
    if (threadIdx.x == 0) {
        unsigned cum = meta[8 + n]; int B2 = 0; bool done = false;
        for (int seg = 255; seg >= 0 && !done; --seg) {
            if (cum + psum[seg] >= TOPK) {
                for (int b = seg * 16 + 15; b >= seg * 16; --b) {
                    if (cum + h[b] >= TOPK) { B2 = b; done = true; break; }
                    cum += h[b];
                }
            } else cum += psum[seg];
        }
        meta[16 + n] = ((meta[n] << 12) | (unsigned)B2) << 8;
    }
}

// ---- compact candidates >= threshold (wave-aggregated atomics) ----
__global__ void __launch_bounds__(256)
kcompact(const float* __restrict__ scores, const unsigned* __restrict__ meta,
         unsigned* cnt, unsigned long long* cand) {
    int i = blockIdx.x * 256 + threadIdx.x;   // exact grid: TOTAL/256 blocks
    int n  = i / PERIMG;                      // wave never spans images (PERIMG%64==0)
    int li = i % PERIMG;
    unsigned key = flipKey(scores[i]);
    bool sel = key >= meta[16 + n];
    unsigned long long msk = __ballot(sel);
    if (msk) {
        int lane = threadIdx.x & 63;
        int leader = __ffsll((unsigned long long)msk) - 1;
        unsigned base = 0;
        if (lane == leader) base = atomicAdd(&cnt[n], (unsigned)__popcll(msk));
        base = (unsigned)__shfl((int)base, leader);
        if (sel) {
            unsigned p = base + (unsigned)__popcll(msk & ((1ull << lane) - 1ull));
            if (p < CAP)
                cand[n * CAP + p] =
                    ((unsigned long long)key << 32) | (unsigned)(~li);
        }
    }
}

// ---- per-image: sort, decode, bitmask-parallel class NMS, output ----
__global__ void __launch_bounds__(1024)
knms(const unsigned long long* __restrict__ cand, const unsigned* __restrict__ cnt,
     const float* __restrict__ anchors, const float* __restrict__ breg,
     float* __restrict__ outBoxes, float* __restrict__ outScores,
     float* __restrict__ outLabels) {
    __shared__ unsigned long long sbuf[CAP];         // 16 KB
    __shared__ float ob0[TOPK], ob1[TOPK], ob2[TOPK], ob3[TOPK], area[TOPK];
    __shared__ unsigned long long sup[TOPK];         // 8 KB
    __shared__ unsigned short lbl[TOPK];
    __shared__ unsigned char  keepf[TOPK];
    __shared__ unsigned short clist[TOPK];
    __shared__ unsigned short wrank[TOPK];
    __shared__ unsigned short cstart[NC + 1];
    __shared__ unsigned short ccnt[NC];
    __shared__ int pfx[1024];
    __shared__ int smax;

    int n = blockIdx.x;
    int t = threadIdx.x;
    int M = min(cnt[n], (unsigned)CAP);
    for (int i = t; i < CAP; i += 1024)
        sbuf[i] = (i < M) ? cand[n * CAP + i] : 0ULL;
    __syncthreads();

    // bitonic sort, descending (value desc, then idx asc via ~idx low bits)
    for (int k = 2; k <= CAP; k <<= 1) {
        for (int j = k >> 1; j > 0; j >>= 1) {
            for (int i = t; i < CAP; i += 1024) {
                int l = i ^ j;
                if (l > i) {
                    unsigned long long a = sbuf[i], b = sbuf[l];
                    bool sw = ((i & k) == 0) ? (a < b) : (a > b);
                    if (sw) { sbuf[i] = b; sbuf[l] = a; }
                }
            }
            __syncthreads();
        }
    }

    // decode top-1000 (offset boxes + validity); one pass, no loop
    if (t < TOPK) {
        unsigned long long e = sbuf[t];
        unsigned key = (unsigned)(e >> 32);
        bool real = (t < M) && (key > 0x80000000u);
        unsigned li = ~(unsigned)(e & 0xFFFFFFFFu);
        int k = (int)(li / NC), c = (int)(li % NC);
        int label = c + 1;
        float x1 = 0, y1 = 0, x2 = 0, y2 = 0;
        bool val = false;
        if (real) {
            float a0 = anchors[k * 4 + 0], a1 = anchors[k * 4 + 1];
            float a2 = anchors[k * 4 + 2], a3 = anchors[k * 4 + 3];
            float r0 = breg[(n * 4 + 0) * HWQ + k];
            float r1 = breg[(n * 4 + 1) * HWQ + k];
            float r2 = breg[(n * 4 + 2) * HWQ + k];
            float r3 = breg[(n * 4 + 3) * HWQ + k];
            float aw = a2 - a0, ah = a3 - a1;
            float acx = a0 + 0.5f * aw, acy = a1 + 0.5f * ah;
            float dx = r0 / 10.0f, dy = r1 / 10.0f;
            float dw = fminf(r2 / 5.0f, 4.135166556742356f);
            float dh = fminf(r3 / 5.0f, 4.135166556742356f);
            float pcx = dx * aw + acx, pcy = dy * ah + acy;
            float pw = expf(dw) * aw, ph = expf(dh) * ah;
            x1 = fminf(fmaxf(pcx - 0.5f * pw, 0.0f), 1216.0f);
            y1 = fminf(fmaxf(pcy - 0.5f * ph, 0.0f), 800.0f);
            x2 = fminf(fmaxf(pcx + 0.5f * pw, 0.0f), 1216.0f);
            y2 = fminf(fmaxf(pcy + 0.5f * ph, 0.0f), 800.0f);
            val = (x2 - x1 > 0.0f) && (y2 - y1 > 0.0f);
        }
        float off = (float)label * 10000.0f;   // replicate offset-then-round
        ob0[t] = x1 + off; ob1[t] = y1 + off;
        ob2[t] = x2 + off; ob3[t] = y2 + off;
        area[t] = (ob2[t] - ob0[t]) * (ob3[t] - ob1[t]);
        lbl[t] = real ? (unsigned short)label : (unsigned short)0;
        keepf[t] = val ? 1 : 0;
        sup[t] = 0ULL;
    }
    __syncthreads();

    // per-class counts (order-preserving lists)
    if (t < NC) {
        int cc = 0;
        for (int r = 0; r < TOPK; ++r)
            if (lbl[r] == t + 1) cc++;
        ccnt[t] = (unsigned short)cc;
    }
    __syncthreads();
    if (t == 0) {
        unsigned s = 0; int mx = 0;
        for (int c = 0; c < NC; ++c) {
            cstart[c] = (unsigned short)s; s += ccnt[c];
            if (ccnt[c] > mx) mx = ccnt[c];
        }
        cstart[NC] = (unsigned short)s;
        smax = mx;
    }
    __syncthreads();
    if (t < NC) {
        int w = cstart[t];
        for (int r = 0; r < TOPK; ++r)
            if (lbl[r] == t + 1) { wrank[r] = (unsigned short)(w - cstart[t]); clist[w++] = (unsigned short)r; }
    }
    __syncthreads();

    int mx = smax;
    if (mx <= 64) {
        // parallel pairwise suppression masks: thread per candidate
        if (t < TOPK && lbl[t]) {
            int base = cstart[lbl[t] - 1];
            int w = wrank[t];
            float A0 = ob0[t], A1 = ob1[t], A2 = ob2[t], A3 = ob3[t], Aa = area[t];
            unsigned long long m = 0ULL;
            for (int j = 0; j < w; ++j) {
                int ib = clist[base + j];
                float iw = fminf(A2, ob2[ib]) - fmaxf(A0, ob0[ib]);
                float ih = fminf(A3, ob3[ib]) - fmaxf(A1, ob1[ib]);
                float inter = fmaxf(iw, 0.0f) * fmaxf(ih, 0.0f);
                float denom = Aa + area[ib] - inter + 1e-6f;
                if (inter / denom > 0.6f) m |= (1ull << j);
            }
            sup[t] = m;
        }
        __syncthreads();
        // serial resolve per class: only against previously-KEPT bits
        if (t < NC) {
            unsigned long long kb = 0ULL;
            int base = cstart[t], mc = ccnt[t];
            for (int w = 0; w < mc; ++w) {
                int i = clist[base + w];
                bool kp = keepf[i] && ((sup[i] & kb) == 0ULL);
                keepf[i] = kp ? 1 : 0;
                if (kp) kb |= (1ull << w);
            }
        }
    } else {
        __syncthreads();
        // fallback: serial greedy per class (rare; exact)
        if (t < NC) {
            int s0 = cstart[t], s1 = s0 + ccnt[t];
            for (int a = s0; a < s1; ++a) {
                int ia = clist[a];
                if (!keepf[ia]) continue;
                float A0 = ob0[ia], A1 = ob1[ia], A2 = ob2[ia], A3 = ob3[ia];
                float Aa = area[ia];
                for (int b = a + 1; b < s1; ++b) {
                    int ib = clist[b];
                    if (!keepf[ib]) continue;
                    float iw = fminf(A2, ob2[ib]) - fmaxf(A0, ob0[ib]);
                    float ih = fminf(A3, ob3[ib]) - fmaxf(A1, ob1[ib]);
                    float inter = fmaxf(iw, 0.0f) * fmaxf(ih, 0.0f);
                    float denom = Aa + area[ib] - inter + 1e-6f;
                    if (inter / denom > 0.6f) keepf[ib] = 0;
                }
            }
        }
    }
    __syncthreads();

    // parallel prefix sum over keep flags -> output slots
    pfx[t] = (t < TOPK) ? (int)keepf[t] : 0;
    __syncthreads();
    for (int off = 1; off < 1024; off <<= 1) {
        int add = (t >= off) ? pfx[t - off] : 0;
        __syncthreads();
        pfx[t] += add;
        __syncthreads();
    }
    int total = pfx[1023];

    if (t < TOPK && keepf[t]) {
        int q = pfx[t] - 1;
        if (q < NPOST) {
            // recompute decoded (non-offset) box for output
            unsigned long long e = sbuf[t];
            unsigned li = ~(unsigned)(e & 0xFFFFFFFFu);
            int k = (int)(li / NC);
            float a0 = anchors[k * 4 + 0], a1 = anchors[k * 4 + 1];
            float a2 = anchors[k * 4 + 2], a3 = anchors[k * 4 + 3];
            float r0 = breg[(n * 4 + 0) * HWQ + k];
            float r1 = breg[(n * 4 + 1) * HWQ + k];
            float r2 = breg[(n * 4 + 2) * HWQ + k];
            float r3 = breg[(n * 4 + 3) * HWQ + k];
            float aw = a2 - a0, ah = a3 - a1;
            float acx = a0 + 0.5f * aw, acy = a1 + 0.5f * ah;
            float dx = r0 / 10.0f, dy = r1 / 10.0f;
            float dw = fminf(r2 / 5.0f, 4.135166556742356f);
            float dh = fminf(r3 / 5.0f, 4.135166556742356f);
            float pcx = dx * aw + acx, pcy = dy * ah + acy;
            float pw = expf(dw) * aw, ph = expf(dh) * ah;
            float x1 = fminf(fmaxf(pcx - 0.5f * pw, 0.0f), 1216.0f);
            float y1 = fminf(fmaxf(pcy - 0.5f * ph, 0.0f), 800.0f);
            float x2 = fminf(fmaxf(pcx + 0.5f * pw, 0.0f), 1216.0f);
            float y2 = fminf(fmaxf(pcy + 0.5f * ph, 0.0f), 800.0f);
            float fused = unflipKey((unsigned)(e >> 32));
            outBoxes[(n * NPOST + q) * 4 + 0] = x1;
            outBoxes[(n * NPOST + q) * 4 + 1] = y1;
            outBoxes[(n * NPOST + q) * 4 + 2] = x2;
            outBoxes[(n * NPOST + q) * 4 + 3] = y2;
            outScores[n * NPOST + q] = sqrtf(fmaxf(fused, 0.0f));
            outLabels[n * NPOST + q] = (float)lbl[t];
        }
    }
    if (t < NPOST && t >= total) {
        outBoxes[(n * NPOST + t) * 4 + 0] = 0.0f;
        outBoxes[(n * NPOST + t) * 4 + 1] = 0.0f;
        outBoxes[(n * NPOST + t) * 4 + 2] = 0.0f;
        outBoxes[(n * NPOST + t) * 4 + 3] = 0.0f;
        outScores[n * NPOST + t] = 0.0f;
        outLabels[n * NPOST + t] = 0.0f;
    }
}

extern "C" void kernel_launch(void* const* d_in, const int* in_sizes, int n_in,
                              void* d_out, int out_size, void* d_ws, size_t ws_size,
                              hipStream_t stream) {
    const float* breg = (const float*)d_in[0];   // [8,4,100,152]
    const float* cent = (const float*)d_in[1];   // [8,1,100,152]
    // d_in[2] box_cls: unused by reference
    const float* dp   = (const float*)d_in[3];   // [8,15200,256]
    const float* anc  = (const float*)d_in[4];   // [15200,4]
    const float* pm   = (const float*)d_in[5];   // [80,256]

    char* ws = (char*)d_ws;
    size_t off_scores = 0;                               // 38,912,000 B
    size_t off_ctr    = off_scores + (size_t)TOTAL * 4;
    size_t off_gh     = off_ctr + (size_t)NIMG * HWQ * 4;
    size_t off_fh     = off_gh + (size_t)NIMG * 4096 * 4;
    size_t off_cnt    = off_fh + (size_t)NIMG * 4096 * 4;
    size_t off_meta   = off_cnt + 256;
    size_t off_cand   = off_meta + 256;
    size_t off_nnz    = off_cand + (size_t)NIMG * CAP * 8;
    size_t off_tok    = off_nnz + 512;
    size_t off_wt     = off_tok + (size_t)NC * NL * 4;
    size_t needed     = off_wt + (size_t)NC * NL * 4;
    if (ws_size < needed) return;

    float*    scores = (float*)(ws + off_scores);
    float*    ctr    = (float*)(ws + off_ctr);
    unsigned* gh     = (unsigned*)(ws + off_gh);
    unsigned* fh     = (unsigned*)(ws + off_fh);
    unsigned* cnt    = (unsigned*)(ws + off_cnt);
    unsigned* meta   = (unsigned*)(ws + off_meta);
    unsigned long long* cand = (unsigned long long*)(ws + off_cand);
    unsigned* nnz    = (unsigned*)(ws + off_nnz);
    unsigned* tok    = (unsigned*)(ws + off_tok);
    float*    wt     = (float*)(ws + off_wt);

    // zero histograms + counters (gh, fh, cnt are contiguous)
    hipMemsetAsync(ws + off_gh, 0,
                   (size_t)NIMG * 4096 * 4 * 2 + 32, stream);

    kprep<<<1, 128, 0, stream>>>(pm, nnz, tok, wt);
    kctr<<<(NIMG * HWQ + 255) / 256, 256, 0, stream>>>(cent, ctr);
    kscoreh<<<NIMG * SBLK, 256, 0, stream>>>(dp, ctr, nnz, tok, wt, scores, gh);
    kfind1<<<NIMG, 256, 0, stream>>>(gh, meta);
    khist2<<<TOTAL / 256, 256, 0, stream>>>(scores, meta, fh);
    kfind2<<<NIMG, 256, 0, stream>>>(fh, meta);
    kcompact<<<TOTAL / 256, 256, 0, stream>>>(scores, meta, cnt, cand);

    float* outBoxes  = (float*)d_out;                       // 8*100*4
    float* outScores = outBoxes + NIMG * NPOST * 4;         // 8*100
    float* outLabels = outScores + NIMG * NPOST;            // 8*100
    knms<<<NIMG, 1024, 0, stream>>>(cand, cnt, anc, breg,
                                    outBoxes, outScores, outLabels);
}